// Round 1
// 197.974 us; speedup vs baseline: 1.0037x; 1.0037x over previous
//
#include <hip/hip_runtime.h>
#include <hip/hip_fp16.h>
#include <math.h>

#define N_NODES 50000
#define N_EDGES 800000
#define N_GRAPHS 512
#define NBKT 196                          // 256-node buckets
#define SENT N_NODES
#define CAP_T 6144                        // tmp slots/bucket (max bucket edges ~4300)
#define CAP_S 12288                       // sorted slots/bucket (interleaved CSR, ~7200 typ)
#define EPB 2048                          // edges per binA block
#define NBLK_A 391                        // ceil(800000/2048)
#define N_GROUPS 6250                     // 50000/8
#define NBLK_G 1563                       // ceil(6250/4)

typedef float v2f __attribute__((ext_vector_type(2)));

// workspace byte offsets (256B-aligned)
#define OFF_BCNT    0u                    // 196 ints (zeroed by memset)
#define OFF_DINV    1024u                 // 50000 floats
#define OFF_GGRP    201216u               // 6272 int2 {slot base, K loop bound}
#define OFF_TMP     251392u               // 196*6144 uints
#define OFF_SORTED  5068288u              // 196*12288 ints
#define OFF_XS8_1   14702080u             // 50001*64 bytes fp8
#define OFF_XS8_2   17902336u             // 50001*64 bytes fp8
#define OFF_H2      21102592u             // 50000*64 fp16

// ---- binA: LDS-sort 2048 edges by bucket; dense copy-out to bucket runs ----
__global__ __launch_bounds__(256) void binA(const int* __restrict__ src, const int* __restrict__ dst,
                                            int* __restrict__ bcnt, unsigned int* __restrict__ tmp,
                                            unsigned int* __restrict__ x1, unsigned int* __restrict__ x2) {
    __shared__ int cnt[256];
    __shared__ int lo[256];
    __shared__ int cnt2[256];
    __shared__ int baseg[256];
    __shared__ unsigned int ldsPK[EPB];
    __shared__ int ldsDST[EPB];
    int t = threadIdx.x;
    cnt[t] = 0; cnt2[t] = 0;
    if (blockIdx.x == 0) {                 // zero fp8 sentinel row 50000 of both tables
        if (t < 16) x1[N_NODES * 16 + t] = 0;
        else if (t < 32) x2[N_NODES * 16 + (t - 16)] = 0;
    }
    __syncthreads();
    int e0 = blockIdx.x * EPB;
    int nE = N_EDGES - e0; if (nE > EPB) nE = EPB;
    int sA[8], dA[8];
#pragma unroll
    for (int i = 0; i < 8; ++i) {
        int e = e0 + i * 256 + t;
        if (e < N_EDGES) {
            sA[i] = src[e];
            dA[i] = dst[e];
            atomicAdd(&cnt[dA[i] >> 8], 1);
        } else dA[i] = -1;
    }
    __syncthreads();
    {
        int v = cnt[t];
        lo[t] = v;
        __syncthreads();
        for (int d = 1; d < 256; d <<= 1) {
            int a = (t >= d) ? lo[t - d] : 0;
            __syncthreads();
            lo[t] += a;
            __syncthreads();
        }
        int ex = lo[t] - v;
        __syncthreads();
        lo[t] = ex;
        baseg[t] = (t < NBKT && v) ? atomicAdd(&bcnt[t], v) : 0;
    }
    __syncthreads();
#pragma unroll
    for (int i = 0; i < 8; ++i) {
        if (dA[i] >= 0) {
            int b = dA[i] >> 8;
            int pl = lo[b] + atomicAdd(&cnt2[b], 1);
            ldsPK[pl] = (unsigned int)sA[i] | ((unsigned int)(dA[i] & 255) << 17);  // src < 2^17
            ldsDST[pl] = b * CAP_T + baseg[b] + (pl - lo[b]);
        }
    }
    __syncthreads();
    for (int p = t; p < nE; p += 256)
        tmp[ldsDST[p]] = ldsPK[p];
}

// ---- binB2: build interleaved group-CSR in LDS; dense int4 write-out ----
// Layout: group g (8 nodes), entry k of node (g*8+s) lives at slot gbase[g] + k*8 + s.
// Entry 0 = self index; entries padded with SENT to K (=round4(group max count)) + 4 extra.
__global__ __launch_bounds__(256) void binB2(const unsigned int* __restrict__ tmp,
                                             const int* __restrict__ bcnt,
                                             int* __restrict__ sorted, int2* __restrict__ ggrp,
                                             float* __restrict__ dinv) {
    __shared__ int cnt[256];
    __shared__ int lbs[256];
    __shared__ int cur[256];
    __shared__ int gK[32];
    __shared__ int gpre[33];
    __shared__ int ldsS[CAP_S];
    int b = blockIdx.x, t = threadIdx.x;
    cnt[t] = 0;
    __syncthreads();
    int m = bcnt[b];
    const unsigned int* tp = tmp + b * CAP_T;
    for (int e = t; e < m; e += 256) atomicAdd(&cnt[tp[e] >> 17], 1);
    __syncthreads();
    int node = b * 256 + t;
    int real = node < N_NODES;
    int deg = cnt[t];
    int count = real ? deg + 1 : 0;        // +1: self loop
    int mx = count;
    mx = max(mx, __shfl_xor(mx, 1));
    mx = max(mx, __shfl_xor(mx, 2));
    mx = max(mx, __shfl_xor(mx, 4));
    int K = (mx + 3) & ~3;                 // loop bound, multiple of 4 (0 for empty groups)
    int KP = K + 4;                        // allocated entries (extra quad: guard-free prefetch)
    if ((t & 7) == 0) gK[t >> 3] = KP;
    __syncthreads();
    if (t == 0) {
        int s = 0;
        for (int g = 0; g < 32; ++g) { gpre[g] = s; s += gK[g]; }
        gpre[32] = s;
    }
    __syncthreads();
    int lb = 8 * gpre[t >> 3] + (t & 7);
    lbs[t] = lb;
    cur[t] = real ? 1 : 0;
    if (real) {
        dinv[node] = rsqrtf(1.0f + (float)deg);
        ldsS[lb] = node;                   // self loop at entry 0
    }
    if ((t & 7) == 0) ggrp[b * 32 + (t >> 3)] = make_int2(b * CAP_S + 8 * gpre[t >> 3], K);
    __syncthreads();
    for (int e = t; e < m; e += 256) {
        unsigned int pk = tp[e];
        int d = (int)(pk >> 17);
        int j = atomicAdd(&cur[d], 1);
        ldsS[lbs[d] + j * 8] = (int)(pk & 0x1FFFFu);
    }
    __syncthreads();
    for (int j = cur[t]; j < KP; ++j) ldsS[lb + j * 8] = SENT;
    __syncthreads();
    int ptot = 8 * gpre[32];
    int4* dst4 = (int4*)(sorted + b * CAP_S);
    const int4* src4 = (const int4*)ldsS;
    for (int p = t; p < (ptot >> 2); p += 256) dst4[p] = src4[p];
}

// ---- GEMM layer 1: xs8 = fp8((X @ W1) * dinv[row]), K=128 ----
__global__ __launch_bounds__(256) void gemm1(const float* __restrict__ X, const float* __restrict__ W,
                                             const float* __restrict__ dinv, unsigned int* __restrict__ xs8) {
    __shared__ float sW[128 * 64];
    __shared__ float sX[16 * 132];
    int tid = threadIdx.x;
    {
        const float4* ws = (const float4*)W;
        float4* wd = (float4*)sW;
        for (int i = tid; i < 2048; i += 256) wd[i] = ws[i];
    }
    int row0 = blockIdx.x * 16;
    {
        const float4* xs = (const float4*)(X + row0 * 128);
        for (int i = tid; i < 512; i += 256) {
            int r = i >> 5, q = i & 31;
            *(float4*)&sX[r * 132 + 4 * q] = xs[r * 32 + q];
        }
    }
    __syncthreads();
    int r = tid >> 4;
    int cg = (tid & 15) * 4;
    int row = row0 + r;
    float a0 = 0, a1 = 0, a2 = 0, a3 = 0;
#pragma unroll 8
    for (int k = 0; k < 128; ++k) {
        float xv = sX[r * 132 + k];
        float4 w = *(const float4*)&sW[k * 64 + cg];
        a0 += xv * w.x; a1 += xv * w.y; a2 += xv * w.z; a3 += xv * w.w;
    }
    float s = dinv[row];
    unsigned int pk = 0;
    pk = __builtin_amdgcn_cvt_pk_fp8_f32(a0 * s, a1 * s, pk, false);
    pk = __builtin_amdgcn_cvt_pk_fp8_f32(a2 * s, a3 * s, pk, true);
    xs8[row * 16 + (cg >> 2)] = pk;
}

// ---- shared fp8-row accumulate ----
#define ADD_ROW(rv) { \
    v2f f0 = __builtin_amdgcn_cvt_pk_f32_fp8((rv).x, false); \
    v2f f1 = __builtin_amdgcn_cvt_pk_f32_fp8((rv).x, true); \
    v2f f2 = __builtin_amdgcn_cvt_pk_f32_fp8((rv).y, false); \
    v2f f3 = __builtin_amdgcn_cvt_pk_f32_fp8((rv).y, true); \
    a0 += f0.x; a1 += f0.y; a2 += f1.x; a3 += f1.y; \
    a4 += f2.x; a5 += f2.y; a6 += f3.x; a7 += f3.y; }

// Per-wave: 8 nodes (sub = node-in-group), lane (sub,frag) privately accumulates
// cols frag*8..+7 of node grp*8+sub. No cross-lane reduction, no flush logic.
#define GATHER_ACC() \
    int lane = threadIdx.x & 63; \
    int sub = lane >> 3, frag = lane & 7; \
    int node = grp * 8 + sub; \
    int2 gi = ggrp[grp]; \
    int K = gi.y; \
    const int* sp = sorted + gi.x + sub; \
    const uint2* xr = (const uint2*)xs8 + frag; \
    float a0 = 0, a1 = 0, a2 = 0, a3 = 0, a4 = 0, a5 = 0, a6 = 0, a7 = 0; \
    int i0 = sp[0], i1 = sp[8], i2 = sp[16], i3 = sp[24]; \
    for (int k = 0; k < K; k += 4) { \
        uint2 r0 = xr[i0 * 8]; \
        uint2 r1 = xr[i1 * 8]; \
        uint2 r2 = xr[i2 * 8]; \
        uint2 r3 = xr[i3 * 8]; \
        const int* np = sp + (k + 4) * 8; \
        i0 = np[0]; i1 = np[8]; i2 = np[16]; i3 = np[24]; \
        ADD_ROW(r0); ADD_ROW(r1); ADD_ROW(r2); ADD_ROW(r3); \
    }

// ---- gather layer 1 + fused W2 GEMM: h rows -> LDS; block epilogue emits xs8_2 ----
__global__ __launch_bounds__(256) void gather_fuse(const unsigned char* __restrict__ xs8,
                                                   const int2* __restrict__ ggrp,
                                                   const int* __restrict__ sorted,
                                                   const float* __restrict__ dinv,
                                                   const float* __restrict__ bias,
                                                   const float* __restrict__ W2,
                                                   unsigned int* __restrict__ xs8o) {
    __shared__ float sW2[64 * 64];
    __shared__ float sH[32][68];           // stride 68: bank-conflict-free + 16B-aligned rows
    {
        const float4* ws = (const float4*)W2;
        float4* wd = (float4*)sW2;
        for (int i = threadIdx.x; i < 1024; i += 256) wd[i] = ws[i];
    }
    int wvl = threadIdx.x >> 6;            // wave 0..3
    int grp = blockIdx.x * 4 + wvl;        // group of 8 nodes

    GATHER_ACC()

    {
        float dv = dinv[node];
        float4 bA = *(const float4*)(bias + frag * 8);
        float4 bB = *(const float4*)(bias + frag * 8 + 4);
        float4 w0, w1;
        w0.x = fmaxf(a0 * dv + bA.x, 0.0f); w0.y = fmaxf(a1 * dv + bA.y, 0.0f);
        w0.z = fmaxf(a2 * dv + bA.z, 0.0f); w0.w = fmaxf(a3 * dv + bA.w, 0.0f);
        w1.x = fmaxf(a4 * dv + bB.x, 0.0f); w1.y = fmaxf(a5 * dv + bB.y, 0.0f);
        w1.z = fmaxf(a6 * dv + bB.z, 0.0f); w1.w = fmaxf(a7 * dv + bB.w, 0.0f);
        *(float4*)&sH[wvl * 8 + sub][frag * 8] = w0;
        *(float4*)&sH[wvl * 8 + sub][frag * 8 + 4] = w1;
    }
    __syncthreads();
    // block epilogue: xs2[32 nodes x 64] = (sH @ W2) * dinv
    int r = threadIdx.x >> 3;              // 0..31 local node
    int cg = (threadIdx.x & 7) * 8;        // 8 cols
    float b0 = 0, b1 = 0, b2 = 0, b3 = 0, b4 = 0, b5 = 0, b6 = 0, b7 = 0;
#pragma unroll 8
    for (int k = 0; k < 64; ++k) {
        float hv = sH[r][k];
        float4 wa = *(const float4*)&sW2[k * 64 + cg];
        float4 wb = *(const float4*)&sW2[k * 64 + cg + 4];
        b0 += hv * wa.x; b1 += hv * wa.y; b2 += hv * wa.z; b3 += hv * wa.w;
        b4 += hv * wb.x; b5 += hv * wb.y; b6 += hv * wb.z; b7 += hv * wb.w;
    }
    int node2 = blockIdx.x * 32 + r;
    if (node2 < N_NODES) {
        float s = dinv[node2];
        unsigned int p0 = 0, p1 = 0;
        p0 = __builtin_amdgcn_cvt_pk_fp8_f32(b0 * s, b1 * s, p0, false);
        p0 = __builtin_amdgcn_cvt_pk_fp8_f32(b2 * s, b3 * s, p0, true);
        p1 = __builtin_amdgcn_cvt_pk_fp8_f32(b4 * s, b5 * s, p1, false);
        p1 = __builtin_amdgcn_cvt_pk_fp8_f32(b6 * s, b7 * s, p1, true);
        *(uint2*)(xs8o + node2 * 16 + (cg >> 2)) = make_uint2(p0, p1);
    }
}

// ---- gather layer 2: writes h2 as fp16 ----
__global__ __launch_bounds__(256) void gather_h2(const unsigned char* __restrict__ xs8,
                                                 const int2* __restrict__ ggrp,
                                                 const int* __restrict__ sorted,
                                                 const float* __restrict__ dinv,
                                                 const float* __restrict__ bias,
                                                 __half* __restrict__ h2) {
    int grp = blockIdx.x * 4 + (threadIdx.x >> 6);

    GATHER_ACC()

    if (node < N_NODES) {
        float dv = dinv[node];
        float4 bA = *(const float4*)(bias + frag * 8);
        float4 bB = *(const float4*)(bias + frag * 8 + 4);
        float v0 = fmaxf(a0 * dv + bA.x, 0.0f), v1 = fmaxf(a1 * dv + bA.y, 0.0f);
        float v2 = fmaxf(a2 * dv + bA.z, 0.0f), v3 = fmaxf(a3 * dv + bA.w, 0.0f);
        float v4 = fmaxf(a4 * dv + bB.x, 0.0f), v5 = fmaxf(a5 * dv + bB.y, 0.0f);
        float v6 = fmaxf(a6 * dv + bB.z, 0.0f), v7 = fmaxf(a7 * dv + bB.w, 0.0f);
        __half2 p0 = __floats2half2_rn(v0, v1), p1 = __floats2half2_rn(v2, v3);
        __half2 p2 = __floats2half2_rn(v4, v5), p3 = __floats2half2_rn(v6, v7);
        uint4 pk;
        pk.x = *(unsigned int*)&p0; pk.y = *(unsigned int*)&p1;
        pk.z = *(unsigned int*)&p2; pk.w = *(unsigned int*)&p3;
        *(uint4*)(h2 + node * 64 + frag * 8) = pk;
    }
}

// ---- fused pool (segmented mean over sorted batch) + fc head + log_softmax ----
__device__ __forceinline__ int lower_bound(const int* __restrict__ a, int n, int v) {
    int lo = 0, hi = n;
    while (lo < hi) { int m = (lo + hi) >> 1; if (a[m] < v) lo = m + 1; else hi = m; }
    return lo;
}

__global__ __launch_bounds__(256) void pool_head(const __half* __restrict__ h2,
                                                 const int* __restrict__ batch,
                                                 const float* __restrict__ Wfc, const float* __restrict__ bfc,
                                                 const int* __restrict__ y, float* __restrict__ out) {
    __shared__ int s_beg, s_end;
    __shared__ float sh[4][64];
    __shared__ float pl[64];
    __shared__ float lg[4];
    int g = blockIdx.x;
    int t = threadIdx.x;
    if (t == 0) s_beg = lower_bound(batch, N_NODES, g);
    if (t == 1) s_end = lower_bound(batch, N_NODES, g + 1);
    __syncthreads();
    int beg = s_beg, end = s_end;
    int f = t & 63, seg = t >> 6;
    float s = 0.0f;
    for (int r = beg + seg; r < end; r += 4) s += __half2float(h2[r * 64 + f]);
    sh[seg][f] = s;
    __syncthreads();
    if (t < 64) {
        float p = sh[0][t] + sh[1][t] + sh[2][t] + sh[3][t];
        pl[t] = p / fmaxf((float)(end - beg), 1.0f);
    }
    __syncthreads();
    if (t < 4) {
        float l = bfc[t];
#pragma unroll
        for (int k = 0; k < 64; ++k) l += pl[k] * Wfc[k * 4 + t];
        lg[t] = l;
    }
    __syncthreads();
    if (t == 0) {
        float l0 = lg[0], l1 = lg[1], l2 = lg[2], l3 = lg[3];
        float m = fmaxf(fmaxf(l0, l1), fmaxf(l2, l3));
        float ss = expf(l0 - m) + expf(l1 - m) + expf(l2 - m) + expf(l3 - m);
        float lse = m + logf(ss);
        out[g * 4 + 0] = l0 - lse;
        out[g * 4 + 1] = l1 - lse;
        out[g * 4 + 2] = l2 - lse;
        out[g * 4 + 3] = l3 - lse;
        out[N_GRAPHS * 4 + g] = (float)y[g];
    }
}

extern "C" void kernel_launch(void* const* d_in, const int* in_sizes, int n_in,
                              void* d_out, int out_size, void* d_ws, size_t ws_size,
                              hipStream_t stream) {
    const float* x     = (const float*)d_in[0];
    const int*   ei    = (const int*)d_in[1];
    const int*   batch = (const int*)d_in[2];
    const int*   y     = (const int*)d_in[3];
    const float* W1    = (const float*)d_in[4];
    const float* b1    = (const float*)d_in[5];
    const float* W2    = (const float*)d_in[6];
    const float* b2    = (const float*)d_in[7];
    const float* Wfc   = (const float*)d_in[8];
    const float* bfc   = (const float*)d_in[9];
    float* out = (float*)d_out;

    const int* src = ei;
    const int* dst = ei + N_EDGES;

    char* wsb = (char*)d_ws;
    int*          bcnt   = (int*)(wsb + OFF_BCNT);
    float*        dinv   = (float*)(wsb + OFF_DINV);
    int2*         ggrp   = (int2*)(wsb + OFF_GGRP);
    unsigned int* tmp    = (unsigned int*)(wsb + OFF_TMP);
    int*          sorted = (int*)(wsb + OFF_SORTED);
    unsigned int* xs8_1  = (unsigned int*)(wsb + OFF_XS8_1);
    unsigned int* xs8_2  = (unsigned int*)(wsb + OFF_XS8_2);
    __half*       h2     = (__half*)(wsb + OFF_H2);

    hipMemsetAsync(bcnt, 0, 1024u, stream);

    binA<<<NBLK_A, 256, 0, stream>>>(src, dst, bcnt, tmp, xs8_1, xs8_2);
    binB2<<<NBKT, 256, 0, stream>>>(tmp, bcnt, sorted, ggrp, dinv);

    // layer 1: 128 -> 64
    gemm1<<<N_NODES / 16, 256, 0, stream>>>(x, W1, dinv, xs8_1);
    // layer-1 aggregate + relu + fused W2 GEMM -> xs8_2
    gather_fuse<<<NBLK_G, 256, 0, stream>>>((const unsigned char*)xs8_1, ggrp, sorted,
                                            dinv, b1, W2, xs8_2);
    // layer-2 aggregate + relu -> h2 (fp16)
    gather_h2<<<NBLK_G, 256, 0, stream>>>((const unsigned char*)xs8_2, ggrp, sorted,
                                          dinv, b2, h2);

    pool_head<<<N_GRAPHS, 256, 0, stream>>>(h2, batch, Wfc, bfc, y, out);
}

// Round 2
// 173.021 us; speedup vs baseline: 1.1484x; 1.1442x over previous
//
#include <hip/hip_runtime.h>
#include <hip/hip_fp16.h>
#include <math.h>

#define N_NODES 50000
#define N_EDGES 800000
#define N_GRAPHS 512
#define NBKT 196                          // 256-node buckets
#define SENT N_NODES
#define EPB 2048                          // edges per binA block
#define NSEG 391                          // binA blocks = ceil(800000/2048)
#define CAP_C 48                          // slots per (block,bucket) run; max observed ~30
#define NBLK_B2 392                       // half-bucket blocks (128 nodes each)
#define CAP_SH 8192                       // sorted ints per half-bucket (worst-case sum < 6700)
#define NBLK_GM 782                       // gemm blocks (64 rows each)
#define PREP_GRID (NBLK_B2 + NBLK_GM)     // 1174
#define N_GROUPS 6272                     // 392*16 groups of 8 nodes
#define NBLK_G 1568                       // 6272/4 gather blocks

typedef float v2f __attribute__((ext_vector_type(2)));
typedef float f32x4 __attribute__((ext_vector_type(4)));
typedef short s16x8 __attribute__((ext_vector_type(8)));

// workspace byte offsets (256B-aligned)
#define OFF_DINV    0u                    // 50176 floats (incl. sentinel + fake-node pad)
#define OFF_GGRP    200704u               // 6272 int2 {slot base, K loop bound}
#define OFF_CNTM    250880u               // 391*196 ints
#define OFF_TMP     557568u               // 196*391*48 uints = 14,714,112 B
#define OFF_SORTED  15271680u             // 392*8192 ints = 12,845,056 B
#define OFF_XS8_1   28116736u             // 50001*64 B fp8
#define OFF_XS8_2   31316992u             // 50001*64 B fp8
#define OFF_H2      34517248u             // 50000*64 fp16

__device__ __forceinline__ unsigned short f2bf(float f) {   // fp32 -> bf16 bits, RNE
    unsigned int u = __float_as_uint(f);
    u += 0x7FFFu + ((u >> 16) & 1u);
    return (unsigned short)(u >> 16);
}

// ---- binA: fixed-slot binning, no scans, no global atomics, no memset needed ----
__global__ __launch_bounds__(256) void binA(const int* __restrict__ src, const int* __restrict__ dst,
                                            int* __restrict__ cntmat, unsigned int* __restrict__ tmp,
                                            unsigned int* __restrict__ x1, unsigned int* __restrict__ x2,
                                            float* __restrict__ dinv) {
    __shared__ int cnt[256];
    int t = threadIdx.x;
    cnt[t] = 0;
    if (blockIdx.x == 0) {                 // zero fp8 sentinel row 50000 of both tables + dinv sentinel
        if (t < 16) x1[N_NODES * 16 + t] = 0;
        else if (t < 32) x2[N_NODES * 16 + (t - 16)] = 0;
        else if (t == 32) dinv[SENT] = 0.0f;
    }
    __syncthreads();
    int e0 = blockIdx.x * EPB;
#pragma unroll
    for (int i = 0; i < 8; ++i) {
        int e = e0 + i * 256 + t;
        if (e < N_EDGES) {
            int s = src[e], d = dst[e];
            int b = d >> 8;
            int p = atomicAdd(&cnt[b], 1);
            tmp[(b * NSEG + blockIdx.x) * CAP_C + p] =
                (unsigned int)s | ((unsigned int)(d & 255) << 17);   // src < 2^17
        }
    }
    __syncthreads();
    if (t < NBKT) cntmat[blockIdx.x * NBKT + t] = cnt[t];
}

// ---- prep: heterogeneous grid. blocks [0,392): binB2 half-bucket CSR build.
//      blocks [392,1174): bf16-MFMA gemm1 (xs8_1 = fp8(X @ W1), UNSCALED). ----
__global__ __launch_bounds__(256) void prep(const unsigned int* __restrict__ tmp,
                                            const int* __restrict__ cntmat,
                                            int* __restrict__ sorted, int2* __restrict__ ggrp,
                                            float* __restrict__ dinv,
                                            const float* __restrict__ X, const float* __restrict__ W1,
                                            unsigned int* __restrict__ xs8) {
    __shared__ __align__(16) char pool[34816];
    __shared__ int bad;
    int t = threadIdx.x;

    if (blockIdx.x < NBLK_B2) {
        // ---------------- binB2 half-bucket ----------------
        int* cnt  = (int*)pool;              // 128
        int* lbs  = (int*)(pool + 512);      // 128
        int* cur  = (int*)(pool + 1024);     // 128
        int* gK   = (int*)(pool + 1536);     // 16
        int* gpre = (int*)(pool + 1600);     // 17
        int* ldsS = (int*)(pool + 1792);     // 8192
        int b2 = blockIdx.x, bkt = b2 >> 1, half = b2 & 1;
        if (t < 128) cnt[t] = 0;
        __syncthreads();
        // pass A: count degrees of my 128 nodes across 391 segments
        for (int seg = t; seg < NSEG; seg += 256) {
            int c = cntmat[seg * NBKT + bkt];
            const unsigned int* tp = tmp + (bkt * NSEG + seg) * CAP_C;
            for (int e = 0; e < c; ++e) {
                int d = (int)(tp[e] >> 17);
                if ((d >> 7) == half) atomicAdd(&cnt[d & 127], 1);
            }
        }
        __syncthreads();
        int node = 0, deg = 0, K = 0, KP = 0, lb = 0, myreal = 0;
        if (t < 128) {
            node = bkt * 256 + half * 128 + t;
            myreal = node < N_NODES;
            deg = cnt[t];
            int count = myreal ? deg + 1 : 0;        // +1 self loop
            int mx = count;
            mx = max(mx, __shfl_xor(mx, 1));
            mx = max(mx, __shfl_xor(mx, 2));
            mx = max(mx, __shfl_xor(mx, 4));
            K = (mx + 3) & ~3;                       // group loop bound (mult of 4)
            KP = K + 4;                              // +extra quad: guard-free prefetch
            if ((t & 7) == 0) gK[t >> 3] = KP;
        }
        __syncthreads();
        if (t == 0) {
            int s = 0;
#pragma unroll
            for (int g = 0; g < 16; ++g) { gpre[g] = s; s += gK[g]; }
            gpre[16] = s;
        }
        __syncthreads();
        if (t < 128) {
            lb = 8 * gpre[t >> 3] + (t & 7);
            lbs[t] = lb;
            cur[t] = myreal ? 1 : 0;
            if (myreal) {
                dinv[node] = rsqrtf(1.0f + (float)deg);
                ldsS[lb] = node;                     // self loop at entry 0
            }
            if ((t & 7) == 0)
                ggrp[b2 * 16 + (t >> 3)] = make_int2(b2 * CAP_SH + 8 * gpre[t >> 3], K);
        }
        __syncthreads();
        // pass B: scatter my edges
        for (int seg = t; seg < NSEG; seg += 256) {
            int c = cntmat[seg * NBKT + bkt];
            const unsigned int* tp = tmp + (bkt * NSEG + seg) * CAP_C;
            for (int e = 0; e < c; ++e) {
                unsigned int pk = tp[e];
                int d = (int)(pk >> 17);
                if ((d >> 7) == half) {
                    int loc = d & 127;
                    int j = atomicAdd(&cur[loc], 1);
                    ldsS[lbs[loc] + j * 8] = (int)(pk & 0x1FFFFu);
                }
            }
        }
        __syncthreads();
        if (t < 128)
            for (int j = cur[t]; j < KP; ++j) ldsS[lb + j * 8] = SENT;
        __syncthreads();
        int ptot = 8 * gpre[16];
        int4* dst4 = (int4*)(sorted + b2 * CAP_SH);
        const int4* src4 = (const int4*)ldsS;
        for (int p = t; p < (ptot >> 2); p += 256) dst4[p] = src4[p];
    } else {
        // ---------------- gemm1: 64 rows/block, mfma_f32_16x16x32_bf16 ----------------
        short* W1T = (short*)pool;               // [64 cols][136] bf16 bits (padded)
        float* sD  = (float*)(pool + 17408);     // [64 rows][68]
        int gb = blockIdx.x - NBLK_B2;
        int row0 = gb * 64;
        for (int i = t; i < 8192; i += 256) {    // stage W1 transposed to bf16
            int k = i >> 6, c = i & 63;
            W1T[c * 136 + k] = (short)f2bf(W1[i]);
        }
        __syncthreads();
        int w = t >> 6, lane = t & 63;
        int arow = lane & 15, kg = lane >> 4;    // arow = A-row = B-col; kg = k-group
        int r = row0 + w * 16 + arow;
        const float* xp = X + r * 128 + kg * 8;
        bool vr = (r < N_NODES);
        const short* wb = &W1T[arow * 136 + kg * 8];
        f32x4 ac0 = {0.f, 0.f, 0.f, 0.f}, ac1 = ac0, ac2 = ac0, ac3 = ac0;
#pragma unroll
        for (int kk = 0; kk < 4; ++kk) {
            float4 xa, xb;
            if (vr) { xa = *(const float4*)(xp); xb = *(const float4*)(xp + 4); }
            else    { xa = make_float4(0.f, 0.f, 0.f, 0.f); xb = xa; }
            xp += 32;
            s16x8 af;
            af[0] = (short)f2bf(xa.x); af[1] = (short)f2bf(xa.y);
            af[2] = (short)f2bf(xa.z); af[3] = (short)f2bf(xa.w);
            af[4] = (short)f2bf(xb.x); af[5] = (short)f2bf(xb.y);
            af[6] = (short)f2bf(xb.z); af[7] = (short)f2bf(xb.w);
            const short* wk = wb + kk * 32;
            s16x8 bf0 = *(const s16x8*)(wk);
            s16x8 bf1 = *(const s16x8*)(wk + 16 * 136);
            s16x8 bf2 = *(const s16x8*)(wk + 32 * 136);
            s16x8 bf3 = *(const s16x8*)(wk + 48 * 136);
            asm volatile(
                "s_nop 1\n\t"
                "v_mfma_f32_16x16x32_bf16 %0, %4, %5, %0\n\t"
                "v_mfma_f32_16x16x32_bf16 %1, %4, %6, %1\n\t"
                "v_mfma_f32_16x16x32_bf16 %2, %4, %7, %2\n\t"
                "v_mfma_f32_16x16x32_bf16 %3, %4, %8, %3"
                : "+v"(ac0), "+v"(ac1), "+v"(ac2), "+v"(ac3)
                : "v"(af), "v"(bf0), "v"(bf1), "v"(bf2), "v"(bf3));
        }
        asm volatile("s_nop 7\n\ts_nop 7");      // MFMA->VALU read hazard pad
        int dr = w * 16 + kg * 4;                // D row = (lane>>4)*4+reg; col = lane&15
#pragma unroll
        for (int reg = 0; reg < 4; ++reg) {
            sD[(dr + reg) * 68 + arow]      = ac0[reg];
            sD[(dr + reg) * 68 + 16 + arow] = ac1[reg];
            sD[(dr + reg) * 68 + 32 + arow] = ac2[reg];
            sD[(dr + reg) * 68 + 48 + arow] = ac3[reg];
        }
        __syncthreads();
        // self-check 2 elements vs fp32 reference; fallback to scalar if layout wrong
        if (t == 0) {
            float r0v = 0.f, r1v = 0.f;
            const float* x0 = X + row0 * 128;
            for (int k = 0; k < 128; ++k) {
                float wv = W1[k * 64];
                r0v += x0[k] * wv;
                r1v += x0[128 + k] * wv;
            }
            bad = (fabsf(r0v - sD[0])  > 0.05f * fabsf(r0v) + 0.1f) ||
                  (fabsf(r1v - sD[68]) > 0.05f * fabsf(r1v) + 0.1f);
        }
        __syncthreads();
        if (bad) {                               // block-uniform branch
            for (int i = t; i < 4096; i += 256) {
                int lr = i >> 6, c = i & 63;
                int nd = row0 + lr;
                if (nd < N_NODES) {
                    const float* xr2 = X + nd * 128;
                    float s = 0.f;
                    for (int k = 0; k < 128; ++k) s += xr2[k] * W1[k * 64 + c];
                    sD[lr * 68 + c] = s;
                }
            }
            __syncthreads();
        }
        // quantize fp8 (UNSCALED — dinv applied at gather time)
        for (int i = t; i < 1024; i += 256) {
            int lr = i >> 4, q = i & 15;
            int nd = row0 + lr;
            if (nd < N_NODES) {
                float4 v = *(const float4*)&sD[lr * 68 + q * 4];
                unsigned int pk = 0;
                pk = __builtin_amdgcn_cvt_pk_fp8_f32(v.x, v.y, pk, false);
                pk = __builtin_amdgcn_cvt_pk_fp8_f32(v.z, v.w, pk, true);
                xs8[nd * 16 + q] = pk;
            }
        }
    }
}

// ---- shared fp8-row accumulate with per-source dinv scale ----
#define FMA_ROW(rv, ds) { \
    v2f f0 = __builtin_amdgcn_cvt_pk_f32_fp8((rv).x, false); \
    v2f f1 = __builtin_amdgcn_cvt_pk_f32_fp8((rv).x, true); \
    v2f f2 = __builtin_amdgcn_cvt_pk_f32_fp8((rv).y, false); \
    v2f f3 = __builtin_amdgcn_cvt_pk_f32_fp8((rv).y, true); \
    a0 += f0.x * (ds); a1 += f0.y * (ds); a2 += f1.x * (ds); a3 += f1.y * (ds); \
    a4 += f2.x * (ds); a5 += f2.y * (ds); a6 += f3.x * (ds); a7 += f3.y * (ds); }

// Per-wave: 8 nodes (sub = node-in-group); lane (sub,frag) accumulates cols frag*8..+7.
#define GATHER_ACC() \
    int lane = threadIdx.x & 63; \
    int sub = lane >> 3, frag = lane & 7; \
    int node = grp * 8 + sub; \
    int2 gi = ggrp[grp]; \
    int K = gi.y; \
    const int* sp = sorted + gi.x + sub; \
    const uint2* xr = (const uint2*)xs8 + frag; \
    float a0 = 0, a1 = 0, a2 = 0, a3 = 0, a4 = 0, a5 = 0, a6 = 0, a7 = 0; \
    int i0 = sp[0], i1 = sp[8], i2 = sp[16], i3 = sp[24]; \
    for (int k = 0; k < K; k += 4) { \
        uint2 r0 = xr[i0 * 8]; \
        uint2 r1 = xr[i1 * 8]; \
        uint2 r2 = xr[i2 * 8]; \
        uint2 r3 = xr[i3 * 8]; \
        float s0 = dinv[i0], s1 = dinv[i1], s2 = dinv[i2], s3 = dinv[i3]; \
        const int* np = sp + (k + 4) * 8; \
        i0 = np[0]; i1 = np[8]; i2 = np[16]; i3 = np[24]; \
        FMA_ROW(r0, s0); FMA_ROW(r1, s1); FMA_ROW(r2, s2); FMA_ROW(r3, s3); \
    }

// ---- gather layer 1 + fused W2 GEMM: h rows -> LDS; block epilogue emits xs8_2 ----
__global__ __launch_bounds__(256) void gather_fuse(const unsigned char* __restrict__ xs8,
                                                   const int2* __restrict__ ggrp,
                                                   const int* __restrict__ sorted,
                                                   const float* __restrict__ dinv,
                                                   const float* __restrict__ bias,
                                                   const float* __restrict__ W2,
                                                   unsigned int* __restrict__ xs8o) {
    __shared__ float sW2[64 * 64];
    __shared__ float sH[32][68];
    {
        const float4* ws = (const float4*)W2;
        float4* wd = (float4*)sW2;
        for (int i = threadIdx.x; i < 1024; i += 256) wd[i] = ws[i];
    }
    int wvl = threadIdx.x >> 6;
    int grp = blockIdx.x * 4 + wvl;

    GATHER_ACC()

    {
        float dv = dinv[node];
        float4 bA = *(const float4*)(bias + frag * 8);
        float4 bB = *(const float4*)(bias + frag * 8 + 4);
        float4 w0, w1;
        w0.x = fmaxf(a0 * dv + bA.x, 0.0f); w0.y = fmaxf(a1 * dv + bA.y, 0.0f);
        w0.z = fmaxf(a2 * dv + bA.z, 0.0f); w0.w = fmaxf(a3 * dv + bA.w, 0.0f);
        w1.x = fmaxf(a4 * dv + bB.x, 0.0f); w1.y = fmaxf(a5 * dv + bB.y, 0.0f);
        w1.z = fmaxf(a6 * dv + bB.z, 0.0f); w1.w = fmaxf(a7 * dv + bB.w, 0.0f);
        *(float4*)&sH[wvl * 8 + sub][frag * 8] = w0;
        *(float4*)&sH[wvl * 8 + sub][frag * 8 + 4] = w1;
    }
    __syncthreads();
    // block epilogue: xs8_2[32 nodes x 64] = fp8(sH @ W2)  (unscaled)
    int r = threadIdx.x >> 3;
    int cg = (threadIdx.x & 7) * 8;
    float b0 = 0, b1 = 0, b2 = 0, b3 = 0, b4 = 0, b5 = 0, b6 = 0, b7 = 0;
#pragma unroll 8
    for (int k = 0; k < 64; ++k) {
        float hv = sH[r][k];
        float4 wa = *(const float4*)&sW2[k * 64 + cg];
        float4 wbv = *(const float4*)&sW2[k * 64 + cg + 4];
        b0 += hv * wa.x; b1 += hv * wa.y; b2 += hv * wa.z; b3 += hv * wa.w;
        b4 += hv * wbv.x; b5 += hv * wbv.y; b6 += hv * wbv.z; b7 += hv * wbv.w;
    }
    int node2 = blockIdx.x * 32 + r;
    if (node2 < N_NODES) {
        unsigned int p0 = 0, p1 = 0;
        p0 = __builtin_amdgcn_cvt_pk_fp8_f32(b0, b1, p0, false);
        p0 = __builtin_amdgcn_cvt_pk_fp8_f32(b2, b3, p0, true);
        p1 = __builtin_amdgcn_cvt_pk_fp8_f32(b4, b5, p1, false);
        p1 = __builtin_amdgcn_cvt_pk_fp8_f32(b6, b7, p1, true);
        *(uint2*)(xs8o + node2 * 16 + (cg >> 2)) = make_uint2(p0, p1);
    }
}

// ---- gather layer 2: writes h2 as fp16 ----
__global__ __launch_bounds__(256) void gather_h2(const unsigned char* __restrict__ xs8,
                                                 const int2* __restrict__ ggrp,
                                                 const int* __restrict__ sorted,
                                                 const float* __restrict__ dinv,
                                                 const float* __restrict__ bias,
                                                 __half* __restrict__ h2) {
    int grp = blockIdx.x * 4 + (threadIdx.x >> 6);

    GATHER_ACC()

    if (node < N_NODES) {
        float dv = dinv[node];
        float4 bA = *(const float4*)(bias + frag * 8);
        float4 bB = *(const float4*)(bias + frag * 8 + 4);
        float v0 = fmaxf(a0 * dv + bA.x, 0.0f), v1 = fmaxf(a1 * dv + bA.y, 0.0f);
        float v2 = fmaxf(a2 * dv + bA.z, 0.0f), v3 = fmaxf(a3 * dv + bA.w, 0.0f);
        float v4 = fmaxf(a4 * dv + bB.x, 0.0f), v5 = fmaxf(a5 * dv + bB.y, 0.0f);
        float v6 = fmaxf(a6 * dv + bB.z, 0.0f), v7 = fmaxf(a7 * dv + bB.w, 0.0f);
        __half2 p0 = __floats2half2_rn(v0, v1), p1 = __floats2half2_rn(v2, v3);
        __half2 p2 = __floats2half2_rn(v4, v5), p3 = __floats2half2_rn(v6, v7);
        uint4 pk;
        pk.x = *(unsigned int*)&p0; pk.y = *(unsigned int*)&p1;
        pk.z = *(unsigned int*)&p2; pk.w = *(unsigned int*)&p3;
        *(uint4*)(h2 + node * 64 + frag * 8) = pk;
    }
}

// ---- fused pool (segmented mean over sorted batch) + fc head + log_softmax ----
__device__ __forceinline__ int lower_bound(const int* __restrict__ a, int n, int v) {
    int lo = 0, hi = n;
    while (lo < hi) { int m = (lo + hi) >> 1; if (a[m] < v) lo = m + 1; else hi = m; }
    return lo;
}

__global__ __launch_bounds__(256) void pool_head(const __half* __restrict__ h2,
                                                 const int* __restrict__ batch,
                                                 const float* __restrict__ Wfc, const float* __restrict__ bfc,
                                                 const int* __restrict__ y, float* __restrict__ out) {
    __shared__ int s_beg, s_end;
    __shared__ float sh[4][64];
    __shared__ float pl[64];
    __shared__ float lg[4];
    int g = blockIdx.x;
    int t = threadIdx.x;
    if (t == 0) s_beg = lower_bound(batch, N_NODES, g);
    if (t == 1) s_end = lower_bound(batch, N_NODES, g + 1);
    __syncthreads();
    int beg = s_beg, end = s_end;
    int f = t & 63, seg = t >> 6;
    float s = 0.0f;
    for (int r = beg + seg; r < end; r += 4) s += __half2float(h2[r * 64 + f]);
    sh[seg][f] = s;
    __syncthreads();
    if (t < 64) {
        float p = sh[0][t] + sh[1][t] + sh[2][t] + sh[3][t];
        pl[t] = p / fmaxf((float)(end - beg), 1.0f);
    }
    __syncthreads();
    if (t < 4) {
        float l = bfc[t];
#pragma unroll
        for (int k = 0; k < 64; ++k) l += pl[k] * Wfc[k * 4 + t];
        lg[t] = l;
    }
    __syncthreads();
    if (t == 0) {
        float l0 = lg[0], l1 = lg[1], l2 = lg[2], l3 = lg[3];
        float m = fmaxf(fmaxf(l0, l1), fmaxf(l2, l3));
        float ss = expf(l0 - m) + expf(l1 - m) + expf(l2 - m) + expf(l3 - m);
        float lse = m + logf(ss);
        out[g * 4 + 0] = l0 - lse;
        out[g * 4 + 1] = l1 - lse;
        out[g * 4 + 2] = l2 - lse;
        out[g * 4 + 3] = l3 - lse;
        out[N_GRAPHS * 4 + g] = (float)y[g];
    }
}

extern "C" void kernel_launch(void* const* d_in, const int* in_sizes, int n_in,
                              void* d_out, int out_size, void* d_ws, size_t ws_size,
                              hipStream_t stream) {
    const float* x     = (const float*)d_in[0];
    const int*   ei    = (const int*)d_in[1];
    const int*   batch = (const int*)d_in[2];
    const int*   y     = (const int*)d_in[3];
    const float* W1    = (const float*)d_in[4];
    const float* b1    = (const float*)d_in[5];
    const float* W2    = (const float*)d_in[6];
    const float* b2    = (const float*)d_in[7];
    const float* Wfc   = (const float*)d_in[8];
    const float* bfc   = (const float*)d_in[9];
    float* out = (float*)d_out;

    const int* src = ei;
    const int* dst = ei + N_EDGES;

    char* wsb = (char*)d_ws;
    float*        dinv   = (float*)(wsb + OFF_DINV);
    int2*         ggrp   = (int2*)(wsb + OFF_GGRP);
    int*          cntmat = (int*)(wsb + OFF_CNTM);
    unsigned int* tmp    = (unsigned int*)(wsb + OFF_TMP);
    int*          sorted = (int*)(wsb + OFF_SORTED);
    unsigned int* xs8_1  = (unsigned int*)(wsb + OFF_XS8_1);
    unsigned int* xs8_2  = (unsigned int*)(wsb + OFF_XS8_2);
    __half*       h2     = (__half*)(wsb + OFF_H2);

    binA<<<NSEG, 256, 0, stream>>>(src, dst, cntmat, tmp, xs8_1, xs8_2, dinv);
    // binB2 (half-buckets) + gemm1 (bf16 MFMA) run concurrently in one dispatch
    prep<<<PREP_GRID, 256, 0, stream>>>(tmp, cntmat, sorted, ggrp, dinv, x, W1, xs8_1);
    // layer-1 aggregate (per-src dinv fma) + relu + fused W2 GEMM -> xs8_2
    gather_fuse<<<NBLK_G, 256, 0, stream>>>((const unsigned char*)xs8_1, ggrp, sorted,
                                            dinv, b1, W2, xs8_2);
    // layer-2 aggregate + relu -> h2 (fp16)
    gather_h2<<<NBLK_G, 256, 0, stream>>>((const unsigned char*)xs8_2, ggrp, sorted,
                                          dinv, b2, h2);
    pool_head<<<N_GRAPHS, 256, 0, stream>>>(h2, batch, Wfc, bfc, y, out);
}